// Round 1
// baseline (395.071 us; speedup 1.0000x reference)
//
#include <hip/hip_runtime.h>
#include <hip/hip_bf16.h>

typedef __attribute__((ext_vector_type(4))) float  f32x4;
typedef __attribute__((ext_vector_type(8))) short  bf16x8;
typedef __attribute__((ext_vector_type(4))) int    int32x4;
typedef __attribute__((ext_vector_type(2))) unsigned int uint32x2;

#define DEVINL static __device__ __forceinline__

DEVINL ushort f2bf(float f) {
  unsigned u = __builtin_bit_cast(unsigned, f);
  unsigned r = u + 0x7fffu + ((u >> 16) & 1u);
  return (ushort)(r >> 16);
}

DEVINL f32x4 mfma16(bf16x8 a, bf16x8 b, f32x4 c) {
  return __builtin_amdgcn_mfma_f32_16x16x32_bf16(a, b, c, 0, 0, 0);
}

// C = A @ B.  A [M,K] (f32 or bf16), B [K,N] f32 (cast to bf16 in staging).
// MODE 0: C f32 [M,N] + bias
// MODE 1: C bf16 scattered to [b,h,n,d]   (N=512: col = h*64+d, row = b*2048+n)
// MODE 2: C bf16 scattered to [b,h,d,n]   (V transposed for attention PV)
template<bool ABF, int MODE>
__global__ __launch_bounds__(256)
void gemm_k(const void* __restrict__ Ap, const float* __restrict__ Bp,
            void* __restrict__ Cp, const float* __restrict__ bias,
            int M, int N, int K)
{
  __shared__ ushort As[128 * 40];
  __shared__ ushort Bs[128 * 40];
  const int t  = threadIdx.x;
  const int m0 = blockIdx.y * 128, n0 = blockIdx.x * 128;
  const int lane = t & 63, w = t >> 6;
  const int wr = w >> 1, wc = w & 1;
  const int g = lane >> 4, ql = lane & 15;

  const int arow = t >> 1, akc = (t & 1) * 16;   // A staging: 1 row x 16 k per thread
  const int bgr = t >> 5, blc = (t & 31) * 4;    // B staging: 4 k-rows x 4 cols per thread

  f32x4 acc[4][4];
  #pragma unroll
  for (int i = 0; i < 4; i++)
    #pragma unroll
    for (int j = 0; j < 4; j++) acc[i][j] = (f32x4){0.f, 0.f, 0.f, 0.f};

  for (int k0 = 0; k0 < K; k0 += 32) {
    // ---- stage A tile [128][32] -> As[row][k], padded stride 40
    {
      ushort* dst = &As[arow * 40 + akc];
      if (ABF) {
        const ushort* ap = (const ushort*)Ap + (size_t)(m0 + arow) * K + k0 + akc;
        *(bf16x8*)dst       = *(const bf16x8*)ap;
        *(bf16x8*)(dst + 8) = *(const bf16x8*)(ap + 8);
      } else {
        const float* ap = (const float*)Ap + (size_t)(m0 + arow) * K + k0 + akc;
        f32x4 v0 = *(const f32x4*)(ap + 0);
        f32x4 v1 = *(const f32x4*)(ap + 4);
        f32x4 v2 = *(const f32x4*)(ap + 8);
        f32x4 v3 = *(const f32x4*)(ap + 12);
        bf16x8 h0, h1;
        #pragma unroll
        for (int i = 0; i < 4; i++) {
          h0[i]     = (short)f2bf(v0[i]);
          h0[i + 4] = (short)f2bf(v1[i]);
          h1[i]     = (short)f2bf(v2[i]);
          h1[i + 4] = (short)f2bf(v3[i]);
        }
        *(bf16x8*)dst       = h0;
        *(bf16x8*)(dst + 8) = h1;
      }
    }
    // ---- stage B tile transposed: Bs[col][k] (col-major panel), padded stride 40
    {
      const float* bp = Bp + (size_t)(k0 + bgr * 4) * N + n0 + blc;
      f32x4 r0 = *(const f32x4*)(bp);
      f32x4 r1 = *(const f32x4*)(bp + N);
      f32x4 r2 = *(const f32x4*)(bp + 2 * N);
      f32x4 r3 = *(const f32x4*)(bp + 3 * N);
      #pragma unroll
      for (int j = 0; j < 4; j++) {
        uint32x2 pr;
        pr[0] = ((unsigned)f2bf(r1[j]) << 16) | f2bf(r0[j]);
        pr[1] = ((unsigned)f2bf(r3[j]) << 16) | f2bf(r2[j]);
        *(uint32x2*)&Bs[(blc + j) * 40 + bgr * 4] = pr;
      }
    }
    __syncthreads();

    bf16x8 af[4], bfr[4];
    #pragma unroll
    for (int i = 0; i < 4; i++)
      af[i] = *(const bf16x8*)&As[(wr * 64 + i * 16 + ql) * 40 + g * 8];
    #pragma unroll
    for (int i = 0; i < 4; i++)
      bfr[i] = *(const bf16x8*)&Bs[(wc * 64 + i * 16 + ql) * 40 + g * 8];
    #pragma unroll
    for (int i = 0; i < 4; i++)
      #pragma unroll
      for (int j = 0; j < 4; j++)
        acc[i][j] = mfma16(af[i], bfr[j], acc[i][j]);
    __syncthreads();
  }

  // ---- epilogue.  D layout: row = 4*(lane>>4)+r, col = lane&15
  #pragma unroll
  for (int i = 0; i < 4; i++) {
    #pragma unroll
    for (int j = 0; j < 4; j++) {
      int col = n0 + wc * 64 + j * 16 + ql;
      #pragma unroll
      for (int r = 0; r < 4; r++) {
        int mrow = m0 + wr * 64 + i * 16 + g * 4 + r;
        float v = acc[i][j][r];
        if (MODE == 0) {
          ((float*)Cp)[(size_t)mrow * N + col] = v + bias[col];
        } else {
          int b = mrow >> 11, nn = mrow & 2047;
          int hh = col >> 6, dd = col & 63;
          size_t base = (size_t)(b * 8 + hh) * 131072;
          if (MODE == 1) ((ushort*)Cp)[base + (size_t)nn * 64 + dd]  = f2bf(v);
          else           ((ushort*)Cp)[base + (size_t)dd * 2048 + nn] = f2bf(v);
        }
      }
    }
  }
}

// Flash attention.  Q,K: [bh][n][64] bf16, V: [bh][64][n] bf16 (transposed), mask int32 [b][j].
// 4 waves x 16 q-rows per block; j-tiles of 32; swapped QK^T (S^T = K.Q^T) so softmax
// reduction is 2 shfl_xor; P repacked across lane groups into PV A-fragment layout.
__global__ __launch_bounds__(256)
void attn_k(const ushort* __restrict__ Qb, const ushort* __restrict__ Kb,
            const ushort* __restrict__ VT, const int* __restrict__ msk,
            ushort* __restrict__ AO)
{
  const int bh = blockIdx.x, b = bh >> 3, h = bh & 7;
  const int t = threadIdx.x, lane = t & 63, w = t >> 6;
  const int g = lane >> 4, ql = lane & 15;
  const int q0 = blockIdx.y * 64 + w * 16;

  const ushort* Qh = Qb + (size_t)bh * 131072;
  const ushort* Kh = Kb + (size_t)bh * 131072;
  const ushort* Vh = VT + (size_t)bh * 131072;
  const int* mp = msk + b * 2048;

  const bf16x8 qf0 = *(const bf16x8*)(Qh + (size_t)(q0 + ql) * 64 + 8 * g);
  const bf16x8 qf1 = *(const bf16x8*)(Qh + (size_t)(q0 + ql) * 64 + 32 + 8 * g);

  f32x4 o0 = {0.f,0.f,0.f,0.f}, o1 = o0, o2 = o0, o3 = o0;
  float m = -1e30f, lsum = 0.f;
  const f32x4 fz = {0.f,0.f,0.f,0.f};
  const float sc = 0.18033688011112042f;  // (1/8) * log2(e)

  for (int j0 = 0; j0 < 2048; j0 += 32) {
    const ushort* kp = Kh + (size_t)(j0 + ql) * 64 + 8 * g;
    bf16x8 k00 = *(const bf16x8*)(kp);
    bf16x8 k01 = *(const bf16x8*)(kp + 32);
    bf16x8 k10 = *(const bf16x8*)(kp + 1024);
    bf16x8 k11 = *(const bf16x8*)(kp + 1024 + 32);

    f32x4 s0 = mfma16(k00, qf0, fz); s0 = mfma16(k01, qf1, s0);
    f32x4 s1 = mfma16(k10, qf0, fz); s1 = mfma16(k11, qf1, s1);

    int32x4 m0v = *(const int32x4*)(mp + j0 + 4 * g);
    int32x4 m1v = *(const int32x4*)(mp + j0 + 16 + 4 * g);

    float pv[8];
    #pragma unroll
    for (int r = 0; r < 4; r++) {
      pv[r]     = m0v[r] ? s0[r] * sc : -3.0e38f;
      pv[r + 4] = m1v[r] ? s1[r] * sc : -3.0e38f;
    }
    float pm = pv[0];
    #pragma unroll
    for (int i = 1; i < 8; i++) pm = fmaxf(pm, pv[i]);
    pm = fmaxf(pm, __shfl_xor(pm, 16));
    pm = fmaxf(pm, __shfl_xor(pm, 32));
    float mn = fmaxf(m, pm);
    float alpha = exp2f(m - mn);
    float rs = 0.f;
    #pragma unroll
    for (int i = 0; i < 8; i++) { pv[i] = exp2f(pv[i] - mn); rs += pv[i]; }
    rs += __shfl_xor(rs, 16);
    rs += __shfl_xor(rs, 32);
    lsum = lsum * alpha + rs;
    m = mn;

    unsigned pk0 = ((unsigned)f2bf(pv[1]) << 16) | f2bf(pv[0]);
    unsigned pk1 = ((unsigned)f2bf(pv[3]) << 16) | f2bf(pv[2]);
    unsigned pk2 = ((unsigned)f2bf(pv[5]) << 16) | f2bf(pv[4]);
    unsigned pk3 = ((unsigned)f2bf(pv[7]) << 16) | f2bf(pv[6]);

    // repack P^T (D-layout) -> PV A-fragment (k = 8g+i)
    const int srcA = ((g & 1) << 5) + ql;   // group (g&1)*2
    const int srcB = srcA + 16;             // group (g&1)*2 + 1
    unsigned a0 = __shfl(pk0, srcA), a1 = __shfl(pk1, srcA);
    unsigned a2 = __shfl(pk2, srcA), a3 = __shfl(pk3, srcA);
    unsigned c0 = __shfl(pk0, srcB), c1 = __shfl(pk1, srcB);
    unsigned c2 = __shfl(pk2, srcB), c3 = __shfl(pk3, srcB);
    const bool hs = (g >> 1) != 0;
    union { unsigned u[4]; bf16x8 v; } pa;
    pa.u[0] = hs ? a2 : a0;
    pa.u[1] = hs ? a3 : a1;
    pa.u[2] = hs ? c2 : c0;
    pa.u[3] = hs ? c3 : c1;

    f32x4 arv;
    #pragma unroll
    for (int r = 0; r < 4; r++) arv[r] = __shfl(alpha, 4 * g + r);

    const ushort* vp = Vh + (size_t)ql * 2048 + j0 + 8 * g;
    bf16x8 v0f = *(const bf16x8*)(vp);
    bf16x8 v1f = *(const bf16x8*)(vp + 16 * 2048);
    bf16x8 v2f = *(const bf16x8*)(vp + 32 * 2048);
    bf16x8 v3f = *(const bf16x8*)(vp + 48 * 2048);

    o0 = mfma16(pa.v, v0f, o0 * arv);
    o1 = mfma16(pa.v, v1f, o1 * arv);
    o2 = mfma16(pa.v, v2f, o2 * arv);
    o3 = mfma16(pa.v, v3f, o3 * arv);
  }

  f32x4 linv;
  #pragma unroll
  for (int r = 0; r < 4; r++) linv[r] = 1.0f / __shfl(lsum, 4 * g + r);
  o0 *= linv; o1 *= linv; o2 *= linv; o3 *= linv;

  #pragma unroll
  for (int r = 0; r < 4; r++) {
    int q = q0 + 4 * g + r;
    size_t rowoff = ((size_t)(b * 2048 + q)) * 512 + h * 64 + ql;
    AO[rowoff]      = f2bf(o0[r]);
    AO[rowoff + 16] = f2bf(o1[r]);
    AO[rowoff + 32] = f2bf(o2[r]);
    AO[rowoff + 48] = f2bf(o3[r]);
  }
}

extern "C" void kernel_launch(void* const* d_in, const int* in_sizes, int n_in,
                              void* d_out, int out_size, void* d_ws, size_t ws_size,
                              hipStream_t stream)
{
  const float* x   = (const float*)d_in[0];
  const float* ctx = (const float*)d_in[1];
  const int*   mk  = (const int*)d_in[2];
  const float* Wq  = (const float*)d_in[3];
  const float* Wk  = (const float*)d_in[4];
  const float* Wv  = (const float*)d_in[5];
  const float* Wo  = (const float*)d_in[6];
  const float* bo  = (const float*)d_in[7];
  float* out = (float*)d_out;

  ushort* Qb = (ushort*)d_ws;          // [32][2048][64] bf16 = 8 MB
  ushort* Kb = Qb + 4194304;           // 8 MB
  ushort* VT = Kb + 4194304;           // 8 MB  (transposed [32][64][2048])
  ushort* AO = VT + 4194304;           // 8 MB

  gemm_k<false, 1><<<dim3(4, 64), 256, 0, stream>>>(x,   Wq, Qb, nullptr, 8192, 512, 1024);
  gemm_k<false, 1><<<dim3(4, 64), 256, 0, stream>>>(ctx, Wk, Kb, nullptr, 8192, 512, 768);
  gemm_k<false, 2><<<dim3(4, 64), 256, 0, stream>>>(ctx, Wv, VT, nullptr, 8192, 512, 768);
  attn_k<<<dim3(32, 32), 256, 0, stream>>>(Qb, Kb, VT, mk, AO);
  gemm_k<true, 0><<<dim3(8, 64), 256, 0, stream>>>(AO, Wo, out, bo, 8192, 1024, 512);
}

// Round 2
// 290.995 us; speedup vs baseline: 1.3577x; 1.3577x over previous
//
#include <hip/hip_runtime.h>
#include <hip/hip_bf16.h>

typedef __attribute__((ext_vector_type(4)))  float  f32x4;
typedef __attribute__((ext_vector_type(16))) float  f32x16;
typedef __attribute__((ext_vector_type(8)))  short  bf16x8;
typedef __attribute__((ext_vector_type(4)))  int    int32x4;
typedef __attribute__((ext_vector_type(2)))  unsigned int uint32x2;

#define DEVINL static __device__ __forceinline__

DEVINL ushort f2bf(float f) {
  unsigned u = __builtin_bit_cast(unsigned, f);
  unsigned r = u + 0x7fffu + ((u >> 16) & 1u);
  return (ushort)(r >> 16);
}

DEVINL unsigned cvtpk(float lo, float hi) {
  unsigned r;
  asm("v_cvt_pk_bf16_f32 %0, %1, %2" : "=v"(r) : "v"(lo), "v"(hi));
  return r;
}

DEVINL void plswap(unsigned &a, unsigned &b) {
  asm("v_permlane32_swap_b32 %0, %1" : "+v"(a), "+v"(b));
}

DEVINL f32x4 mfma16(bf16x8 a, bf16x8 b, f32x4 c) {
  return __builtin_amdgcn_mfma_f32_16x16x32_bf16(a, b, c, 0, 0, 0);
}
DEVINL f32x16 mfma32(bf16x8 a, bf16x8 b, f32x16 c) {
  return __builtin_amdgcn_mfma_f32_32x32x16_bf16(a, b, c, 0, 0, 0);
}

// C = A @ B.  A [M,K] (f32 or bf16), B [K,N] f32 (cast to bf16 in staging).
// MODE 0: C f32 [M,N] + bias
// MODE 1: C bf16 scattered to [b,h,n,d]   (N=512: col = h*64+d, row = b*2048+n)
// MODE 2: C bf16 scattered to [b,h,d,n]   (V transposed for attention PV)
template<bool ABF, int MODE>
__global__ __launch_bounds__(256)
void gemm_k(const void* __restrict__ Ap, const float* __restrict__ Bp,
            void* __restrict__ Cp, const float* __restrict__ bias,
            int M, int N, int K)
{
  __shared__ ushort As[128 * 40];
  __shared__ ushort Bs[128 * 40];
  const int t  = threadIdx.x;
  const int m0 = blockIdx.y * 128, n0 = blockIdx.x * 128;
  const int lane = t & 63, w = t >> 6;
  const int wr = w >> 1, wc = w & 1;
  const int g = lane >> 4, ql = lane & 15;

  const int arow = t >> 1, akc = (t & 1) * 16;
  const int bgr = t >> 5, blc = (t & 31) * 4;

  f32x4 acc[4][4];
  #pragma unroll
  for (int i = 0; i < 4; i++)
    #pragma unroll
    for (int j = 0; j < 4; j++) acc[i][j] = (f32x4){0.f, 0.f, 0.f, 0.f};

  for (int k0 = 0; k0 < K; k0 += 32) {
    {
      ushort* dst = &As[arow * 40 + akc];
      if (ABF) {
        const ushort* ap = (const ushort*)Ap + (size_t)(m0 + arow) * K + k0 + akc;
        *(bf16x8*)dst       = *(const bf16x8*)ap;
        *(bf16x8*)(dst + 8) = *(const bf16x8*)(ap + 8);
      } else {
        const float* ap = (const float*)Ap + (size_t)(m0 + arow) * K + k0 + akc;
        f32x4 v0 = *(const f32x4*)(ap + 0);
        f32x4 v1 = *(const f32x4*)(ap + 4);
        f32x4 v2 = *(const f32x4*)(ap + 8);
        f32x4 v3 = *(const f32x4*)(ap + 12);
        bf16x8 h0, h1;
        #pragma unroll
        for (int i = 0; i < 4; i++) {
          h0[i]     = (short)f2bf(v0[i]);
          h0[i + 4] = (short)f2bf(v1[i]);
          h1[i]     = (short)f2bf(v2[i]);
          h1[i + 4] = (short)f2bf(v3[i]);
        }
        *(bf16x8*)dst       = h0;
        *(bf16x8*)(dst + 8) = h1;
      }
    }
    {
      const float* bp = Bp + (size_t)(k0 + bgr * 4) * N + n0 + blc;
      f32x4 r0 = *(const f32x4*)(bp);
      f32x4 r1 = *(const f32x4*)(bp + N);
      f32x4 r2 = *(const f32x4*)(bp + 2 * N);
      f32x4 r3 = *(const f32x4*)(bp + 3 * N);
      #pragma unroll
      for (int j = 0; j < 4; j++) {
        uint32x2 pr;
        pr[0] = ((unsigned)f2bf(r1[j]) << 16) | f2bf(r0[j]);
        pr[1] = ((unsigned)f2bf(r3[j]) << 16) | f2bf(r2[j]);
        *(uint32x2*)&Bs[(blc + j) * 40 + bgr * 4] = pr;
      }
    }
    __syncthreads();

    bf16x8 af[4], bfr[4];
    #pragma unroll
    for (int i = 0; i < 4; i++)
      af[i] = *(const bf16x8*)&As[(wr * 64 + i * 16 + ql) * 40 + g * 8];
    #pragma unroll
    for (int i = 0; i < 4; i++)
      bfr[i] = *(const bf16x8*)&Bs[(wc * 64 + i * 16 + ql) * 40 + g * 8];
    #pragma unroll
    for (int i = 0; i < 4; i++)
      #pragma unroll
      for (int j = 0; j < 4; j++)
        acc[i][j] = mfma16(af[i], bfr[j], acc[i][j]);
    __syncthreads();
  }

  #pragma unroll
  for (int i = 0; i < 4; i++) {
    #pragma unroll
    for (int j = 0; j < 4; j++) {
      int col = n0 + wc * 64 + j * 16 + ql;
      #pragma unroll
      for (int r = 0; r < 4; r++) {
        int mrow = m0 + wr * 64 + i * 16 + g * 4 + r;
        float v = acc[i][j][r];
        if (MODE == 0) {
          ((float*)Cp)[(size_t)mrow * N + col] = v + bias[col];
        } else {
          int b = mrow >> 11, nn = mrow & 2047;
          int hh = col >> 6, dd = col & 63;
          size_t base = (size_t)(b * 8 + hh) * 131072;
          if (MODE == 1) ((ushort*)Cp)[base + (size_t)nn * 64 + dd]  = f2bf(v);
          else           ((ushort*)Cp)[base + (size_t)dd * 2048 + nn] = f2bf(v);
        }
      }
    }
  }
}

// Flash attention, fully-transposed 32x32 scheme.
// Q,K: [bh][n][64] bf16; V: [bh][64][n] bf16 (transposed); mask int32 [b][j].
// Per wave: 32 q-rows.  S^T = K.Q^T (4 mfma32 over d=64) -> lane holds 16 j-vals
// of ONE q column -> softmax state is lane-scalar (no alpha broadcasts).
// P^T -> PV B-fragment via 8 cvt_pk + 4 permlane32_swap (T12).
// O^T = V^T.P^T accumulated in 2x f32x16.  Defer-max rescale (T13, thr=8).
__global__ __launch_bounds__(256)
void attn_k(const ushort* __restrict__ Qb, const ushort* __restrict__ Kb,
            const ushort* __restrict__ VT, const int* __restrict__ msk,
            ushort* __restrict__ AO)
{
  const int bh = blockIdx.x, b = bh >> 3, h = bh & 7;
  const int t = threadIdx.x, lane = t & 63, w = t >> 6;
  const int l31 = lane & 31, hi = lane >> 5;
  const int q0 = blockIdx.y * 128 + w * 32;

  const ushort* Qh = Qb + (size_t)bh * 131072;
  const ushort* Kh = Kb + (size_t)bh * 131072;
  const ushort* Vh = VT + (size_t)bh * 131072;
  const int* mp = msk + b * 2048 + 4 * hi;

  bf16x8 qf[4];
  #pragma unroll
  for (int kk = 0; kk < 4; kk++)
    qf[kk] = *(const bf16x8*)(Qh + (size_t)(q0 + l31) * 64 + kk * 16 + 8 * hi);

  f32x16 o0 = {}, o1 = {};
  float m = -1e30f, lsum = 0.f;
  const float sc = 0.18033688011112042f;  // (1/8) * log2(e)

  for (int j0 = 0; j0 < 2048; j0 += 32) {
    // ---- S^T tile: rows j (16/lane), col q
    const ushort* kp = Kh + (size_t)(j0 + l31) * 64 + 8 * hi;
    bf16x8 kf0 = *(const bf16x8*)(kp);
    bf16x8 kf1 = *(const bf16x8*)(kp + 16);
    bf16x8 kf2 = *(const bf16x8*)(kp + 32);
    bf16x8 kf3 = *(const bf16x8*)(kp + 48);
    f32x16 z = {};
    f32x16 s = mfma32(kf0, qf[0], z);
    s = mfma32(kf1, qf[1], s);
    s = mfma32(kf2, qf[2], s);
    s = mfma32(kf3, qf[3], s);

    // ---- mask + scale.  reg r <-> j_local = (r&3) + 8*(r>>2) + 4*hi
    int32x4 mv0 = *(const int32x4*)(mp + j0);
    int32x4 mv1 = *(const int32x4*)(mp + j0 + 8);
    int32x4 mv2 = *(const int32x4*)(mp + j0 + 16);
    int32x4 mv3 = *(const int32x4*)(mp + j0 + 24);

    float pv[16];
    #pragma unroll
    for (int e = 0; e < 4; e++) {
      pv[e]      = mv0[e] ? s[e]      * sc : -1e30f;
      pv[4 + e]  = mv1[e] ? s[4 + e]  * sc : -1e30f;
      pv[8 + e]  = mv2[e] ? s[8 + e]  * sc : -1e30f;
      pv[12 + e] = mv3[e] ? s[12 + e] * sc : -1e30f;
    }

    // ---- lane-local max over 16, then one cross-half xor
    float pm = pv[0];
    #pragma unroll
    for (int r = 1; r < 16; r++) pm = fmaxf(pm, pv[r]);
    pm = fmaxf(pm, __shfl_xor(pm, 32));

    // ---- defer-max rescale (T13)
    if (!__all(pm <= m + 8.f)) {
      float mn = fmaxf(m, pm);
      float al = exp2f(m - mn);
      lsum *= al;
      #pragma unroll
      for (int r = 0; r < 16; r++) { o0[r] *= al; o1[r] *= al; }
      m = mn;
    }

    float p[16];
    float rs = 0.f;
    #pragma unroll
    for (int r = 0; r < 16; r++) { p[r] = exp2f(pv[r] - m); rs += p[r]; }
    rs += __shfl_xor(rs, 32);
    lsum += rs;

    // ---- pack P^T into PV B-fragments (8 cvt_pk + 4 permlane32_swap)
    unsigned pk01 = cvtpk(p[0],  p[1]),  pk23 = cvtpk(p[2],  p[3]);
    unsigned pk45 = cvtpk(p[4],  p[5]),  pk67 = cvtpk(p[6],  p[7]);
    unsigned pk89 = cvtpk(p[8],  p[9]),  pkAB = cvtpk(p[10], p[11]);
    unsigned pkCD = cvtpk(p[12], p[13]), pkEF = cvtpk(p[14], p[15]);
    plswap(pk01, pk45);   // -> w0, w2 of kk=0 fragment
    plswap(pk23, pk67);   // -> w1, w3
    plswap(pk89, pkCD);   // -> w0, w2 of kk=1 fragment
    plswap(pkAB, pkEF);   // -> w1, w3
    union { unsigned u[4]; bf16x8 v; } pf0, pf1;
    pf0.u[0] = pk01; pf0.u[1] = pk23; pf0.u[2] = pk45; pf0.u[3] = pk67;
    pf1.u[0] = pk89; pf1.u[1] = pkAB; pf1.u[2] = pkCD; pf1.u[3] = pkEF;

    // ---- O^T += V^T . P^T   (rows d, col q)
    const ushort* vp = Vh + (size_t)l31 * 2048 + j0 + 8 * hi;
    bf16x8 vf00 = *(const bf16x8*)(vp);
    bf16x8 vf01 = *(const bf16x8*)(vp + 16);
    bf16x8 vf10 = *(const bf16x8*)(vp + 32 * 2048);
    bf16x8 vf11 = *(const bf16x8*)(vp + 32 * 2048 + 16);
    o0 = mfma32(vf00, pf0.v, o0);
    o0 = mfma32(vf01, pf1.v, o0);
    o1 = mfma32(vf10, pf0.v, o1);
    o1 = mfma32(vf11, pf1.v, o1);
  }

  // ---- epilogue: lane holds O^T[d][q] for one q, 32 d-values
  float inv = 1.0f / lsum;
  const int q = q0 + l31;
  ushort* aor = AO + ((size_t)(b * 2048 + q)) * 512 + h * 64;
  #pragma unroll
  for (int grp = 0; grp < 4; grp++) {
    int d0 = grp * 8 + 4 * hi;
    uint32x2 w0, w1;
    w0[0] = cvtpk(o0[4 * grp] * inv, o0[4 * grp + 1] * inv);
    w0[1] = cvtpk(o0[4 * grp + 2] * inv, o0[4 * grp + 3] * inv);
    w1[0] = cvtpk(o1[4 * grp] * inv, o1[4 * grp + 1] * inv);
    w1[1] = cvtpk(o1[4 * grp + 2] * inv, o1[4 * grp + 3] * inv);
    *(uint32x2*)(aor + d0)      = w0;
    *(uint32x2*)(aor + 32 + d0) = w1;
  }
}

extern "C" void kernel_launch(void* const* d_in, const int* in_sizes, int n_in,
                              void* d_out, int out_size, void* d_ws, size_t ws_size,
                              hipStream_t stream)
{
  const float* x   = (const float*)d_in[0];
  const float* ctx = (const float*)d_in[1];
  const int*   mk  = (const int*)d_in[2];
  const float* Wq  = (const float*)d_in[3];
  const float* Wk  = (const float*)d_in[4];
  const float* Wv  = (const float*)d_in[5];
  const float* Wo  = (const float*)d_in[6];
  const float* bo  = (const float*)d_in[7];
  float* out = (float*)d_out;

  ushort* Qb = (ushort*)d_ws;          // [32][2048][64] bf16 = 8 MB
  ushort* Kb = Qb + 4194304;           // 8 MB
  ushort* VT = Kb + 4194304;           // 8 MB  (transposed [32][64][2048])
  ushort* AO = VT + 4194304;           // 8 MB

  gemm_k<false, 1><<<dim3(4, 64), 256, 0, stream>>>(x,   Wq, Qb, nullptr, 8192, 512, 1024);
  gemm_k<false, 1><<<dim3(4, 64), 256, 0, stream>>>(ctx, Wk, Kb, nullptr, 8192, 512, 768);
  gemm_k<false, 2><<<dim3(4, 64), 256, 0, stream>>>(ctx, Wv, VT, nullptr, 8192, 512, 768);
  attn_k<<<dim3(32, 16), 256, 0, stream>>>(Qb, Kb, VT, mk, AO);
  gemm_k<true, 0><<<dim3(8, 64), 256, 0, stream>>>(AO, Wo, out, bo, 8192, 1024, 512);
}